// Round 3
// baseline (204.783 us; speedup 1.0000x reference)
//
#include <hip/hip_runtime.h>
#include <cstddef>
#include <cstdint>

#define B_  4
#define N_  1024
#define D_  1024
#define H_  16
#define DH  64
#define M_  4096   // B_*N_

#define SC2 0.04508422f   // (1/32) * log2(e)  — folded into Q at gemm epilogue

typedef __attribute__((ext_vector_type(4))) float   f32x4;
typedef __attribute__((ext_vector_type(8))) __bf16  bf16x8;

#define MFMA(a, b, c) __builtin_amdgcn_mfma_f32_16x16x32_bf16((a), (b), (c), 0, 0, 0)
#define GLDS(gp, lp) __builtin_amdgcn_global_load_lds( \
    (__attribute__((address_space(1))) void*)(gp),     \
    (__attribute__((address_space(3))) void*)(lp), 16, 0, 0)

// ---------------------------------------------------------------------------
// convert: fp32 -> bf16 for x (4Mi) and Wq/Wk/Wv/Wc (4x1Mi). [verified R3]
// ---------------------------------------------------------------------------
__global__ __launch_bounds__(256) void convert_k(
    const float* __restrict__ x,  const float* __restrict__ Wq,
    const float* __restrict__ Wk, const float* __restrict__ Wv,
    const float* __restrict__ Wc,
    __bf16* __restrict__ xb, __bf16* __restrict__ wqkvb,
    __bf16* __restrict__ wcb)
{
    const unsigned u = blockIdx.x * 256u + threadIdx.x;
    const unsigned e = u * 8u;
    const float* src;
    __bf16* dst;
    if (e < 4194304u) { src = x + e; dst = xb + e; }
    else {
        const unsigned t2 = e - 4194304u;
        const unsigned wsel = t2 >> 20;
        const unsigned wo = t2 & 1048575u;
        src = (wsel == 0 ? Wq : wsel == 1 ? Wk : wsel == 2 ? Wv : Wc) + wo;
        dst = (wsel < 3 ? wqkvb + (size_t)wsel * 1048576u : wcb) + wo;
    }
    const float4 f0 = *(const float4*)(src);
    const float4 f1 = *(const float4*)(src + 4);
    bf16x8 r;
    r[0] = (__bf16)f0.x; r[1] = (__bf16)f0.y; r[2] = (__bf16)f0.z; r[3] = (__bf16)f0.w;
    r[4] = (__bf16)f1.x; r[5] = (__bf16)f1.y; r[6] = (__bf16)f1.z; r[7] = (__bf16)f1.w;
    *(bf16x8*)dst = r;
}

// ---------------------------------------------------------------------------
// QKV GEMM — R12 8-phase 256^2 template [verified R12: moved off critical
// path]. R13 delta: Q slab epilogue multiplies by SC2 (softmax scale folded
// into Q so attn's exp2 needs no per-element mul; bf16 relative precision
// unaffected by scaling).
// ---------------------------------------------------------------------------
__global__ __launch_bounds__(512, 2) void gemm_qkv256(
    const __bf16* __restrict__ xb, const __bf16* __restrict__ Wb,
    const float* __restrict__ bq, const float* __restrict__ bk,
    const float* __restrict__ bv,
    __bf16* __restrict__ qk_out, __bf16* __restrict__ vT)
{
    __shared__ __bf16 ring[65536];   // [A: 4 x 8192][B: 4 x 8192] = 128KB

    const int tid  = threadIdx.x;
    const int w    = tid >> 6;        // 0..7
    const int lane = tid & 63;
    const int quad = lane >> 4;
    const int l15  = lane & 15;
    const int wr   = w >> 2;          // 0..1  (M half)
    const int wc   = w & 3;           // 0..3  (N quarter)

    const int bid = blockIdx.x;
    const bool VT = (bid >= 128);
    int m0, n0;
    const __bf16 *Ap, *Bp;
    if (!VT) { m0 = (bid >> 3) * 256; n0 = (bid & 7) * 256; Ap = xb; Bp = Wb; }
    else {
        const int v = bid - 128;
        m0 = (v & 3) * 256;           // over e (Wv rows)
        n0 = (v >> 2) * 256;          // over m (xb rows)
        Ap = Wb + (size_t)2 * D_ * D_; Bp = xb;
    }

    const size_t sgl = (size_t)(w * 16 + l15) * D_ + quad * 8;
    const __bf16* Asrc = Ap + (size_t)m0 * D_ + sgl;
    const __bf16* Bsrc = Bp + (size_t)n0 * D_ + sgl;
    __bf16* const ringA = ring;
    __bf16* const ringB = ring + 32768;
    const int sdst = w * 1024;

#define STG_A(tt, h) do {                                               \
    const __bf16* s_ = Asrc + (size_t)(h) * 128 * D_ + (tt) * 64;       \
    __bf16* d_ = ringA + ((((tt) & 1) * 2 + (h)) * 8192) + sdst;        \
    GLDS(s_, d_); GLDS(s_ + 32, d_ + 512); } while (0)
#define STG_B(tt, h) do {                                               \
    const __bf16* s_ = Bsrc + (size_t)(h) * 128 * D_ + (tt) * 64;       \
    __bf16* d_ = ringB + ((((tt) & 1) * 2 + (h)) * 8192) + sdst;        \
    GLDS(s_, d_); GLDS(s_ + 32, d_ + 512); } while (0)

    f32x4 acc[8][4];
    #pragma unroll
    for (int i = 0; i < 8; ++i)
        #pragma unroll
        for (int j = 0; j < 4; ++j)
            acc[i][j] = (f32x4){0.f, 0.f, 0.f, 0.f};

    // prologue: order matters for the vmcnt ledger (oldest = B(0))
    STG_B(0, 0); STG_B(0, 1);
    STG_A(0, 0); STG_A(0, 1);
    STG_B(1, 0); STG_B(1, 1);

    const int rdo = lane * 8;

#define READ_A(q)                                                       \
    afr[0][0] = *(const bf16x8*)(Asl + ((2*(q)  )*2 + 0)*512);          \
    afr[0][1] = *(const bf16x8*)(Asl + ((2*(q)  )*2 + 1)*512);          \
    afr[1][0] = *(const bf16x8*)(Asl + ((2*(q)+1)*2 + 0)*512);          \
    afr[1][1] = *(const bf16x8*)(Asl + ((2*(q)+1)*2 + 1)*512);

#define PHASE_MFMA(q)                                                   \
    __builtin_amdgcn_s_barrier();                                       \
    asm volatile("s_waitcnt lgkmcnt(0)" ::: "memory");                  \
    __builtin_amdgcn_s_setprio(1);                                      \
    _Pragma("unroll")                                                   \
    for (int i = 0; i < 2; ++i)                                         \
      _Pragma("unroll")                                                 \
      for (int nt = 0; nt < 4; ++nt) {                                  \
        acc[2*(q)+i][nt] = MFMA(afr[i][0], bfr[nt][0], acc[2*(q)+i][nt]); \
        acc[2*(q)+i][nt] = MFMA(afr[i][1], bfr[nt][1], acc[2*(q)+i][nt]); \
      }                                                                 \
    __builtin_amdgcn_s_setprio(0);

    for (int t = 0; t < 16; ++t) {
        if (t < 15) asm volatile("s_waitcnt vmcnt(4)" ::: "memory");
        else        asm volatile("s_waitcnt vmcnt(0)" ::: "memory");
        __builtin_amdgcn_s_barrier();

        const __bf16* Asl = ringA + ((t & 1) * 2 + wr) * 8192 + rdo;
        const __bf16* Bsl = ringB + ((t & 1) * 2 + (wc >> 1)) * 8192
                                  + (wc & 1) * 4096 + rdo;
        bf16x8 afr[2][2], bfr[4][2];

        // ---- phase 0 ----
        if (t < 15) STG_A(t + 1, 0);
        #pragma unroll
        for (int nt = 0; nt < 4; ++nt) {
            bfr[nt][0] = *(const bf16x8*)(Bsl + (nt * 2 + 0) * 512);
            bfr[nt][1] = *(const bf16x8*)(Bsl + (nt * 2 + 1) * 512);
        }
        READ_A(0)
        PHASE_MFMA(0)
        __builtin_amdgcn_s_barrier();

        // ---- phase 1 ----
        if (t < 15) STG_A(t + 1, 1);
        READ_A(1)
        PHASE_MFMA(1)
        __builtin_amdgcn_s_barrier();

        // ---- phase 2 ----
        if (t < 14) STG_B(t + 2, 0);
        READ_A(2)
        PHASE_MFMA(2)
        __builtin_amdgcn_s_barrier();

        // ---- phase 3 ----
        if (t < 14) STG_B(t + 2, 1);
        READ_A(3)
        PHASE_MFMA(3)
    }
#undef STG_A
#undef STG_B
#undef READ_A
#undef PHASE_MFMA

    if (!VT) {
        const int zq = n0 >> 10;                  // 0:Q 1:K
        const float* bias = zq ? bk : bq;
        const float qs = zq ? 1.0f : SC2;         // fold softmax scale into Q
        const int nb = (n0 & 1023) + wc * 64;
        float bvv[4];
        #pragma unroll
        for (int nt = 0; nt < 4; ++nt) bvv[nt] = bias[nb + nt * 16 + l15];
        __bf16* C = qk_out + (size_t)zq * M_ * D_;
        #pragma unroll
        for (int mt = 0; mt < 8; ++mt) {
            #pragma unroll
            for (int r = 0; r < 4; ++r) {
                const int row = m0 + wr * 128 + mt * 16 + quad * 4 + r;
                #pragma unroll
                for (int nt = 0; nt < 4; ++nt) {
                    const int col = nb + nt * 16 + l15;
                    const size_t idx = (((size_t)(row >> 10) * H_ + (col >> 6)) * N_
                                        + (row & 1023)) * DH + (col & 63);
                    C[idx] = (__bf16)((acc[mt][nt][r] + bvv[nt]) * qs);
                }
            }
        }
    } else {
        #pragma unroll
        for (int mt = 0; mt < 8; ++mt) {
            #pragma unroll
            for (int r = 0; r < 4; ++r) {
                const int row = m0 + wr * 128 + mt * 16 + quad * 4 + r;   // e
                const float brow = bv[row];
                #pragma unroll
                for (int nt = 0; nt < 4; ++nt) {
                    const int col = n0 + wc * 64 + nt * 16 + l15;         // m
                    const size_t idx = (((size_t)(col >> 10) * H_ + (row >> 6)) * DH
                                        + (row & 63)) * N_ + (col & 1023);
                    vT[idx] = (__bf16)(acc[mt][nt][r] + brow);
                }
            }
        }
    }
}

// ---------------------------------------------------------------------------
// Final projection GEMM — R10's gemm64 MODE0 path [verified; R11 ring null].
// ---------------------------------------------------------------------------
__global__ __launch_bounds__(256, 6) void gemm_out(
    const __bf16* __restrict__ A0, const __bf16* __restrict__ Wb,
    const float* __restrict__ b0, float* __restrict__ Cb)
{
    __shared__ __bf16 As[2048];   // 64x32, frag-ordered (4KB)
    __shared__ __bf16 Bs[4096];   // 128x32, frag-ordered (8KB)

    const int tid  = threadIdx.x;
    const int w    = tid >> 6;
    const int lane = tid & 63;
    const int quad = lane >> 4;
    const int l15  = lane & 15;
    const int wr   = w >> 1, wc = w & 1;

    const int m0 = blockIdx.y * 64;
    const int n0 = blockIdx.x * 128;

    const int Tt = tid >> 6, ko = (tid >> 4) & 3, l = tid & 15;
    const size_t aoff  = (size_t)(m0 + Tt * 16 + l) * D_ + ko * 8;
    const size_t boff1 = (size_t)(n0 + Tt * 16 + l) * D_ + ko * 8;
    const size_t boff2 = boff1 + (size_t)64 * D_;
    __bf16* adst  = As + w * 512;
    __bf16* bdst1 = Bs + w * 512;
    __bf16* bdst2 = Bs + 2048 + w * 512;

    f32x4 acc[2][4];
    #pragma unroll
    for (int i = 0; i < 2; ++i)
        #pragma unroll
        for (int j = 0; j < 4; ++j)
            acc[i][j] = (f32x4){0.f, 0.f, 0.f, 0.f};

    for (int k0 = 0; k0 < D_; k0 += 32) {
        GLDS(A0 + aoff  + k0, adst);
        GLDS(Wb + boff1 + k0, bdst1);
        GLDS(Wb + boff2 + k0, bdst2);
        __syncthreads();

        bf16x8 af[2], bf[4];
        #pragma unroll
        for (int mt = 0; mt < 2; ++mt)
            af[mt] = *(const bf16x8*)(As + (((wr * 2 + mt) * 4 + quad) * 16 + l15) * 8);
        #pragma unroll
        for (int nt = 0; nt < 4; ++nt)
            bf[nt] = *(const bf16x8*)(Bs + (((wc * 4 + nt) * 4 + quad) * 16 + l15) * 8);
        #pragma unroll
        for (int mt = 0; mt < 2; ++mt)
            #pragma unroll
            for (int nt = 0; nt < 4; ++nt)
                acc[mt][nt] = MFMA(af[mt], bf[nt], acc[mt][nt]);
        __syncthreads();
    }

    float bvv[4];
    #pragma unroll
    for (int nt = 0; nt < 4; ++nt)
        bvv[nt] = b0[n0 + wc * 64 + nt * 16 + l15];
    #pragma unroll
    for (int mt = 0; mt < 2; ++mt) {
        #pragma unroll
        for (int r = 0; r < 4; ++r) {
            const int row = m0 + (wr * 2 + mt) * 16 + quad * 4 + r;
            #pragma unroll
            for (int nt = 0; nt < 4; ++nt) {
                const int col = n0 + wc * 64 + nt * 16 + l15;
                Cb[(size_t)row * D_ + col] = acc[mt][nt][r] + bvv[nt];
            }
        }
    }
}

// ---------------------------------------------------------------------------
// MFMA flash attention v6 — R13: double-buffered K/V ring (2x16KB) with ONE
// barrier per K-tile and a free vmcnt(0) drain (loads issued a full iteration
// earlier). Hazard ledger: top-of-iter vmcnt(0)+barrier proves (a) all waves'
// stage(kt) landed, (b) all waves finished iter kt-1 reads of buf[(kt+1)&1]
// -> staging kt+1 post-barrier is safe; Ps is per-wave (lgkmcnt-ordered, no
// barrier). Q is pre-scaled by SC2 at the GEMM epilogue -> exp2 direct.
// T5 setprio around MFMA clusters. LDS 50KB -> 3 blocks/CU.
// ---------------------------------------------------------------------------
#define SP  68

__global__ __launch_bounds__(256, 3) void attn_mfma(
    const __bf16* __restrict__ qh, const __bf16* __restrict__ kh,
    const __bf16* __restrict__ vT, __bf16* __restrict__ ob)
{
    __shared__ __bf16 Ks[2 * 4096];
    __shared__ __bf16 Vs[2 * 4096];
    __shared__ float  Ps[4][16 * SP];

    const int tid  = threadIdx.x;
    const int w    = tid >> 6;
    const int lane = tid & 63;
    const int quad = lane >> 4;
    const int l15  = lane & 15;

    const int bh = blockIdx.x & 63;
    const int qt = blockIdx.x >> 6;
    const int b  = bh >> 4;
    const int h  = bh & 15;

    const __bf16* qp = qh + ((size_t)(b * H_ + h) * N_ + qt * 64 + w * 16 + l15) * DH + quad * 8;
    const bf16x8 qf0 = *(const bf16x8*)(qp);
    const bf16x8 qf1 = *(const bf16x8*)(qp + 32);

    const int c1 = tid, c2 = tid + 256;
    const int nt1 = c1 >> 7, ko1 = (c1 >> 4) & 7, l1 = c1 & 15;
    const int nt2 = c2 >> 7, ko2 = (c2 >> 4) & 7, l2 = c2 & 15;
    const __bf16* khead = kh + (size_t)(b * H_ + h) * N_ * DH;
    const __bf16* vhead = vT + (size_t)(b * H_ + h) * DH * N_;
    const size_t koff1 = (size_t)(nt1 * 16 + l1) * DH + ko1 * 8;
    const size_t koff2 = (size_t)(nt2 * 16 + l2) * DH + ko2 * 8;
    const size_t voff1 = (size_t)(nt1 * 16 + l1) * N_ + ko1 * 8;
    const size_t voff2 = (size_t)(nt2 * 16 + l2) * N_ + ko2 * 8;

#define STG_KV(kt, p) do {                                              \
    const size_t kb_ = (size_t)(kt) * 64;                               \
    GLDS(khead + kb_ * DH + koff1, Ks + (p) * 4096 + w * 512);          \
    GLDS(khead + kb_ * DH + koff2, Ks + (p) * 4096 + 2048 + w * 512);   \
    GLDS(vhead + kb_ + voff1,      Vs + (p) * 4096 + w * 512);          \
    GLDS(vhead + kb_ + voff2,      Vs + (p) * 4096 + 2048 + w * 512);   \
} while (0)

    float psum[4] = {0.f, 0.f, 0.f, 0.f};
    f32x4 Ov[4];
    #pragma unroll
    for (int nt = 0; nt < 4; ++nt) Ov[nt] = (f32x4){0.f, 0.f, 0.f, 0.f};

    STG_KV(0, 0);

    for (int kt = 0; kt < 16; ++kt) {
        // stage(kt) has been in flight for a full iteration -> wait ~free
        asm volatile("s_waitcnt vmcnt(0)" ::: "memory");
        __builtin_amdgcn_s_barrier();
        asm volatile("" ::: "memory");   // no LDS reads hoist above barrier

        if (kt < 15) STG_KV(kt + 1, (kt + 1) & 1);

        const __bf16* Kb = Ks + (kt & 1) * 4096;
        const __bf16* Vb = Vs + (kt & 1) * 4096;

        f32x4 sa[4];
        __builtin_amdgcn_s_setprio(1);
        #pragma unroll
        for (int nt = 0; nt < 4; ++nt) {
            const bf16x8 kf0 = *(const bf16x8*)(Kb + (nt * 128 + quad * 16 + l15) * 8);
            const bf16x8 kf1 = *(const bf16x8*)(Kb + (nt * 128 + (quad + 4) * 16 + l15) * 8);
            sa[nt] = (f32x4){0.f, 0.f, 0.f, 0.f};
            sa[nt] = MFMA(qf0, kf0, sa[nt]);
            sa[nt] = MFMA(qf1, kf1, sa[nt]);
        }
        __builtin_amdgcn_s_setprio(0);

        #pragma unroll
        for (int nt = 0; nt < 4; ++nt) {
            #pragma unroll
            for (int r = 0; r < 4; ++r) {
                const float p = __builtin_exp2f(sa[nt][r]);   // SC2 pre-folded into Q
                psum[r] += p;
                Ps[w][(quad * 4 + r) * SP + nt * 16 + l15] = p;
            }
        }

        __builtin_amdgcn_s_setprio(1);
        #pragma unroll
        for (int kw = 0; kw < 2; ++kw) {
            const f32x4 pa = *(const f32x4*)&Ps[w][l15 * SP + kw * 32 + quad * 8];
            const f32x4 pb = *(const f32x4*)&Ps[w][l15 * SP + kw * 32 + quad * 8 + 4];
            bf16x8 pf;
            #pragma unroll
            for (int j = 0; j < 4; ++j) { pf[j] = (__bf16)pa[j]; pf[4 + j] = (__bf16)pb[j]; }
            #pragma unroll
            for (int nt = 0; nt < 4; ++nt) {
                const bf16x8 vf = *(const bf16x8*)(Vb + (nt * 128 + (kw * 4 + quad) * 16 + l15) * 8);
                Ov[nt] = MFMA(pf, vf, Ov[nt]);
            }
        }
        __builtin_amdgcn_s_setprio(0);
    }
#undef STG_KV

    float lrow[4];
    #pragma unroll
    for (int r = 0; r < 4; ++r) {
        float lt = psum[r];
        lt += __shfl_xor(lt, 1);
        lt += __shfl_xor(lt, 2);
        lt += __shfl_xor(lt, 4);
        lt += __shfl_xor(lt, 8);
        lrow[r] = lt;
    }

    #pragma unroll
    for (int r = 0; r < 4; ++r) {
        const float inv = 1.0f / lrow[r];
        const int row = qt * 64 + w * 16 + quad * 4 + r;
        __bf16* op = ob + ((size_t)(b * H_ + h) * N_ + row) * DH + l15;
        #pragma unroll
        for (int nt = 0; nt < 4; ++nt)
            op[nt * 16] = (__bf16)(Ov[nt][r] * inv);
    }
}

// ---------------------------------------------------------------------------
extern "C" void kernel_launch(void* const* d_in, const int* in_sizes, int n_in,
                              void* d_out, int out_size, void* d_ws, size_t ws_size,
                              hipStream_t stream) {
    const float* x  = (const float*)d_in[0];
    const float* Wq = (const float*)d_in[1];
    const float* bq = (const float*)d_in[2];
    const float* Wk = (const float*)d_in[3];
    const float* bk = (const float*)d_in[4];
    const float* Wv = (const float*)d_in[5];
    const float* bv = (const float*)d_in[6];
    const float* Wc = (const float*)d_in[7];
    const float* bc = (const float*)d_in[8];
    float* out = (float*)d_out;

    // ws layout (48 MB):
    //   [ 0, 8MB): xb (bf16 4Mi) -- dead after QKV GEMM, reused as obf
    //   [ 8,14MB): wqkvb  [14,16MB): wcb
    //   [16,40MB): qkvb (q,k slabs [B,H,N,Dh]; q pre-scaled by SC2)
    //   [40,48MB): vT [B,H,Dh,N] (written directly by gemm_qkv256 V-part)
    char* base = (char*)d_ws;
    __bf16* xb    = (__bf16*)(base);
    __bf16* wqkvb = (__bf16*)(base + (size_t)8  * 1048576);
    __bf16* wcb   = (__bf16*)(base + (size_t)14 * 1048576);
    __bf16* qkvb  = (__bf16*)(base + (size_t)16 * 1048576);
    __bf16* vTb   = (__bf16*)(base + (size_t)40 * 1048576);
    __bf16* obf   = (__bf16*)(base);   // overwrites xb after attn

    __bf16* qhb = qkvb;
    __bf16* khb = qkvb + (size_t)M_ * D_;

    convert_k<<<dim3(4096), dim3(256), 0, stream>>>(
        x, Wq, Wk, Wv, Wc, xb, wqkvb, wcb);

    gemm_qkv256<<<dim3(192), dim3(512), 0, stream>>>(
        xb, wqkvb, bq, bk, bv, qkvb, vTb);

    attn_mfma<<<dim3(1024), dim3(256), 0, stream>>>(qhb, khb, vTb, obf);

    gemm_out<<<dim3(8, 64, 1), dim3(256), 0, stream>>>(obf, wcb, bc, out);
}

// Round 4
// 193.302 us; speedup vs baseline: 1.0594x; 1.0594x over previous
//
#include <hip/hip_runtime.h>
#include <cstddef>
#include <cstdint>

#define B_  4
#define N_  1024
#define D_  1024
#define H_  16
#define DH  64
#define M_  4096   // B_*N_

#define SC2 0.04508422f   // (1/32) * log2(e)  — folded into Q at gemm epilogue

typedef __attribute__((ext_vector_type(4))) float   f32x4;
typedef __attribute__((ext_vector_type(8))) __bf16  bf16x8;

#define MFMA(a, b, c) __builtin_amdgcn_mfma_f32_16x16x32_bf16((a), (b), (c), 0, 0, 0)
#define GLDS(gp, lp) __builtin_amdgcn_global_load_lds( \
    (__attribute__((address_space(1))) void*)(gp),     \
    (__attribute__((address_space(3))) void*)(lp), 16, 0, 0)

// ---------------------------------------------------------------------------
// convert: fp32 -> bf16 for x (4Mi) and Wq/Wk/Wv/Wc (4x1Mi). [verified R3]
// ---------------------------------------------------------------------------
__global__ __launch_bounds__(256) void convert_k(
    const float* __restrict__ x,  const float* __restrict__ Wq,
    const float* __restrict__ Wk, const float* __restrict__ Wv,
    const float* __restrict__ Wc,
    __bf16* __restrict__ xb, __bf16* __restrict__ wqkvb,
    __bf16* __restrict__ wcb)
{
    const unsigned u = blockIdx.x * 256u + threadIdx.x;
    const unsigned e = u * 8u;
    const float* src;
    __bf16* dst;
    if (e < 4194304u) { src = x + e; dst = xb + e; }
    else {
        const unsigned t2 = e - 4194304u;
        const unsigned wsel = t2 >> 20;
        const unsigned wo = t2 & 1048575u;
        src = (wsel == 0 ? Wq : wsel == 1 ? Wk : wsel == 2 ? Wv : Wc) + wo;
        dst = (wsel < 3 ? wqkvb + (size_t)wsel * 1048576u : wcb) + wo;
    }
    const float4 f0 = *(const float4*)(src);
    const float4 f1 = *(const float4*)(src + 4);
    bf16x8 r;
    r[0] = (__bf16)f0.x; r[1] = (__bf16)f0.y; r[2] = (__bf16)f0.z; r[3] = (__bf16)f0.w;
    r[4] = (__bf16)f1.x; r[5] = (__bf16)f1.y; r[6] = (__bf16)f1.z; r[7] = (__bf16)f1.w;
    *(bf16x8*)dst = r;
}

// ---------------------------------------------------------------------------
// QKV GEMM — R12 8-phase 256^2 template [verified R12: moved off critical
// path]. Q slab epilogue multiplies by SC2 (softmax scale folded into Q).
// ---------------------------------------------------------------------------
__global__ __launch_bounds__(512, 2) void gemm_qkv256(
    const __bf16* __restrict__ xb, const __bf16* __restrict__ Wb,
    const float* __restrict__ bq, const float* __restrict__ bk,
    const float* __restrict__ bv,
    __bf16* __restrict__ qk_out, __bf16* __restrict__ vT)
{
    __shared__ __bf16 ring[65536];   // [A: 4 x 8192][B: 4 x 8192] = 128KB

    const int tid  = threadIdx.x;
    const int w    = tid >> 6;        // 0..7
    const int lane = tid & 63;
    const int quad = lane >> 4;
    const int l15  = lane & 15;
    const int wr   = w >> 2;          // 0..1  (M half)
    const int wc   = w & 3;           // 0..3  (N quarter)

    const int bid = blockIdx.x;
    const bool VT = (bid >= 128);
    int m0, n0;
    const __bf16 *Ap, *Bp;
    if (!VT) { m0 = (bid >> 3) * 256; n0 = (bid & 7) * 256; Ap = xb; Bp = Wb; }
    else {
        const int v = bid - 128;
        m0 = (v & 3) * 256;           // over e (Wv rows)
        n0 = (v >> 2) * 256;          // over m (xb rows)
        Ap = Wb + (size_t)2 * D_ * D_; Bp = xb;
    }

    const size_t sgl = (size_t)(w * 16 + l15) * D_ + quad * 8;
    const __bf16* Asrc = Ap + (size_t)m0 * D_ + sgl;
    const __bf16* Bsrc = Bp + (size_t)n0 * D_ + sgl;
    __bf16* const ringA = ring;
    __bf16* const ringB = ring + 32768;
    const int sdst = w * 1024;

#define STG_A(tt, h) do {                                               \
    const __bf16* s_ = Asrc + (size_t)(h) * 128 * D_ + (tt) * 64;       \
    __bf16* d_ = ringA + ((((tt) & 1) * 2 + (h)) * 8192) + sdst;        \
    GLDS(s_, d_); GLDS(s_ + 32, d_ + 512); } while (0)
#define STG_B(tt, h) do {                                               \
    const __bf16* s_ = Bsrc + (size_t)(h) * 128 * D_ + (tt) * 64;       \
    __bf16* d_ = ringB + ((((tt) & 1) * 2 + (h)) * 8192) + sdst;        \
    GLDS(s_, d_); GLDS(s_ + 32, d_ + 512); } while (0)

    f32x4 acc[8][4];
    #pragma unroll
    for (int i = 0; i < 8; ++i)
        #pragma unroll
        for (int j = 0; j < 4; ++j)
            acc[i][j] = (f32x4){0.f, 0.f, 0.f, 0.f};

    // prologue: order matters for the vmcnt ledger (oldest = B(0))
    STG_B(0, 0); STG_B(0, 1);
    STG_A(0, 0); STG_A(0, 1);
    STG_B(1, 0); STG_B(1, 1);

    const int rdo = lane * 8;

#define READ_A(q)                                                       \
    afr[0][0] = *(const bf16x8*)(Asl + ((2*(q)  )*2 + 0)*512);          \
    afr[0][1] = *(const bf16x8*)(Asl + ((2*(q)  )*2 + 1)*512);          \
    afr[1][0] = *(const bf16x8*)(Asl + ((2*(q)+1)*2 + 0)*512);          \
    afr[1][1] = *(const bf16x8*)(Asl + ((2*(q)+1)*2 + 1)*512);

#define PHASE_MFMA(q)                                                   \
    __builtin_amdgcn_s_barrier();                                       \
    asm volatile("s_waitcnt lgkmcnt(0)" ::: "memory");                  \
    __builtin_amdgcn_s_setprio(1);                                      \
    _Pragma("unroll")                                                   \
    for (int i = 0; i < 2; ++i)                                         \
      _Pragma("unroll")                                                 \
      for (int nt = 0; nt < 4; ++nt) {                                  \
        acc[2*(q)+i][nt] = MFMA(afr[i][0], bfr[nt][0], acc[2*(q)+i][nt]); \
        acc[2*(q)+i][nt] = MFMA(afr[i][1], bfr[nt][1], acc[2*(q)+i][nt]); \
      }                                                                 \
    __builtin_amdgcn_s_setprio(0);

    for (int t = 0; t < 16; ++t) {
        if (t < 15) asm volatile("s_waitcnt vmcnt(4)" ::: "memory");
        else        asm volatile("s_waitcnt vmcnt(0)" ::: "memory");
        __builtin_amdgcn_s_barrier();

        const __bf16* Asl = ringA + ((t & 1) * 2 + wr) * 8192 + rdo;
        const __bf16* Bsl = ringB + ((t & 1) * 2 + (wc >> 1)) * 8192
                                  + (wc & 1) * 4096 + rdo;
        bf16x8 afr[2][2], bfr[4][2];

        // ---- phase 0 ----
        if (t < 15) STG_A(t + 1, 0);
        #pragma unroll
        for (int nt = 0; nt < 4; ++nt) {
            bfr[nt][0] = *(const bf16x8*)(Bsl + (nt * 2 + 0) * 512);
            bfr[nt][1] = *(const bf16x8*)(Bsl + (nt * 2 + 1) * 512);
        }
        READ_A(0)
        PHASE_MFMA(0)
        __builtin_amdgcn_s_barrier();

        // ---- phase 1 ----
        if (t < 15) STG_A(t + 1, 1);
        READ_A(1)
        PHASE_MFMA(1)
        __builtin_amdgcn_s_barrier();

        // ---- phase 2 ----
        if (t < 14) STG_B(t + 2, 0);
        READ_A(2)
        PHASE_MFMA(2)
        __builtin_amdgcn_s_barrier();

        // ---- phase 3 ----
        if (t < 14) STG_B(t + 2, 1);
        READ_A(3)
        PHASE_MFMA(3)
    }
#undef STG_A
#undef STG_B
#undef READ_A
#undef PHASE_MFMA

    if (!VT) {
        const int zq = n0 >> 10;                  // 0:Q 1:K
        const float* bias = zq ? bk : bq;
        const float qs = zq ? 1.0f : SC2;         // fold softmax scale into Q
        const int nb = (n0 & 1023) + wc * 64;
        float bvv[4];
        #pragma unroll
        for (int nt = 0; nt < 4; ++nt) bvv[nt] = bias[nb + nt * 16 + l15];
        __bf16* C = qk_out + (size_t)zq * M_ * D_;
        #pragma unroll
        for (int mt = 0; mt < 8; ++mt) {
            #pragma unroll
            for (int r = 0; r < 4; ++r) {
                const int row = m0 + wr * 128 + mt * 16 + quad * 4 + r;
                #pragma unroll
                for (int nt = 0; nt < 4; ++nt) {
                    const int col = nb + nt * 16 + l15;
                    const size_t idx = (((size_t)(row >> 10) * H_ + (col >> 6)) * N_
                                        + (row & 1023)) * DH + (col & 63);
                    C[idx] = (__bf16)((acc[mt][nt][r] + bvv[nt]) * qs);
                }
            }
        }
    } else {
        #pragma unroll
        for (int mt = 0; mt < 8; ++mt) {
            #pragma unroll
            for (int r = 0; r < 4; ++r) {
                const int row = m0 + wr * 128 + mt * 16 + quad * 4 + r;   // e
                const float brow = bv[row];
                #pragma unroll
                for (int nt = 0; nt < 4; ++nt) {
                    const int col = n0 + wc * 64 + nt * 16 + l15;         // m
                    const size_t idx = (((size_t)(col >> 10) * H_ + (row >> 6)) * DH
                                        + (row & 63)) * N_ + (col & 1023);
                    vT[idx] = (__bf16)(acc[mt][nt][r] + brow);
                }
            }
        }
    }
}

// ---------------------------------------------------------------------------
// Final projection GEMM — R10's gemm64 MODE0 path [verified; R11 ring null].
// ---------------------------------------------------------------------------
__global__ __launch_bounds__(256, 6) void gemm_out(
    const __bf16* __restrict__ A0, const __bf16* __restrict__ Wb,
    const float* __restrict__ b0, float* __restrict__ Cb)
{
    __shared__ __bf16 As[2048];   // 64x32, frag-ordered (4KB)
    __shared__ __bf16 Bs[4096];   // 128x32, frag-ordered (8KB)

    const int tid  = threadIdx.x;
    const int w    = tid >> 6;
    const int lane = tid & 63;
    const int quad = lane >> 4;
    const int l15  = lane & 15;
    const int wr   = w >> 1, wc = w & 1;

    const int m0 = blockIdx.y * 64;
    const int n0 = blockIdx.x * 128;

    const int Tt = tid >> 6, ko = (tid >> 4) & 3, l = tid & 15;
    const size_t aoff  = (size_t)(m0 + Tt * 16 + l) * D_ + ko * 8;
    const size_t boff1 = (size_t)(n0 + Tt * 16 + l) * D_ + ko * 8;
    const size_t boff2 = boff1 + (size_t)64 * D_;
    __bf16* adst  = As + w * 512;
    __bf16* bdst1 = Bs + w * 512;
    __bf16* bdst2 = Bs + 2048 + w * 512;

    f32x4 acc[2][4];
    #pragma unroll
    for (int i = 0; i < 2; ++i)
        #pragma unroll
        for (int j = 0; j < 4; ++j)
            acc[i][j] = (f32x4){0.f, 0.f, 0.f, 0.f};

    for (int k0 = 0; k0 < D_; k0 += 32) {
        GLDS(A0 + aoff  + k0, adst);
        GLDS(Wb + boff1 + k0, bdst1);
        GLDS(Wb + boff2 + k0, bdst2);
        __syncthreads();

        bf16x8 af[2], bf[4];
        #pragma unroll
        for (int mt = 0; mt < 2; ++mt)
            af[mt] = *(const bf16x8*)(As + (((wr * 2 + mt) * 4 + quad) * 16 + l15) * 8);
        #pragma unroll
        for (int nt = 0; nt < 4; ++nt)
            bf[nt] = *(const bf16x8*)(Bs + (((wc * 4 + nt) * 4 + quad) * 16 + l15) * 8);
        #pragma unroll
        for (int mt = 0; mt < 2; ++mt)
            #pragma unroll
            for (int nt = 0; nt < 4; ++nt)
                acc[mt][nt] = MFMA(af[mt], bf[nt], acc[mt][nt]);
        __syncthreads();
    }

    float bvv[4];
    #pragma unroll
    for (int nt = 0; nt < 4; ++nt)
        bvv[nt] = b0[n0 + wc * 64 + nt * 16 + l15];
    #pragma unroll
    for (int mt = 0; mt < 2; ++mt) {
        #pragma unroll
        for (int r = 0; r < 4; ++r) {
            const int row = m0 + (wr * 2 + mt) * 16 + quad * 4 + r;
            #pragma unroll
            for (int nt = 0; nt < 4; ++nt) {
                const int col = n0 + wc * 64 + nt * 16 + l15;
                Cb[(size_t)row * D_ + col] = acc[mt][nt][r] + bvv[nt];
            }
        }
    }
}

// ---------------------------------------------------------------------------
// MFMA flash attention v7 — R14: back to R12's single-buffer / 4 blocks/CU
// structure (R13's dbuf lost occupancy: 31->20.9%, net regression), but with
// T14 register staging: tile kt+1 is global-loaded into 16 VGPRs DURING
// compute of tile kt, then ds_written between the two barriers. The vmcnt
// wait on the staged regs lands a full compute phase (~1500cy) after issue
// -> L2 latency hidden at zero LDS/occupancy cost. LDS layout, Ps round-trip,
// softmax path byte-identical to R12 (+ SC2-folded Q, setprio from R13).
// Hazards: barrier#1 of iter kt = all waves drained ds_reads of tile kt-1
// (lgkmcnt in syncthreads) -> safe to overwrite LDS; barrier#2 publishes
// tile kt writes (syncthreads waits lgkmcnt(0)).
// ---------------------------------------------------------------------------
#define SP  68

__global__ __launch_bounds__(256, 4) void attn_mfma(
    const __bf16* __restrict__ qh, const __bf16* __restrict__ kh,
    const __bf16* __restrict__ vT, __bf16* __restrict__ ob)
{
    __shared__ __bf16 Ks[4096];
    __shared__ __bf16 Vs[4096];
    __shared__ float  Ps[4][16 * SP];

    const int tid  = threadIdx.x;
    const int w    = tid >> 6;
    const int lane = tid & 63;
    const int quad = lane >> 4;
    const int l15  = lane & 15;

    const int bh = blockIdx.x & 63;
    const int qt = blockIdx.x >> 6;
    const int b  = bh >> 4;
    const int h  = bh & 15;

    const __bf16* qp = qh + ((size_t)(b * H_ + h) * N_ + qt * 64 + w * 16 + l15) * DH + quad * 8;
    const bf16x8 qf0 = *(const bf16x8*)(qp);
    const bf16x8 qf1 = *(const bf16x8*)(qp + 32);

    // staging decode [verified R8-R12]: chunk c -> (nt, k-octet, row)
    const int c1 = tid, c2 = tid + 256;
    const int nt1 = c1 >> 7, ko1 = (c1 >> 4) & 7, l1 = c1 & 15;
    const int nt2 = c2 >> 7, ko2 = (c2 >> 4) & 7, l2 = c2 & 15;
    const __bf16* khead = kh + (size_t)(b * H_ + h) * N_ * DH;
    const __bf16* vhead = vT + (size_t)(b * H_ + h) * DH * N_;
    const size_t koff1 = (size_t)(nt1 * 16 + l1) * DH + ko1 * 8;
    const size_t koff2 = (size_t)(nt2 * 16 + l2) * DH + ko2 * 8;
    const size_t voff1 = (size_t)(nt1 * 16 + l1) * N_ + ko1 * 8;
    const size_t voff2 = (size_t)(nt2 * 16 + l2) * N_ + ko2 * 8;

    // LDS write addrs: same bytes as the old GLDS dest (uniform base + lane*16B)
    __bf16* const kw1 = Ks + w * 512 + lane * 8;
    __bf16* const kw2 = Ks + 2048 + w * 512 + lane * 8;
    __bf16* const vw1 = Vs + w * 512 + lane * 8;
    __bf16* const vw2 = Vs + 2048 + w * 512 + lane * 8;

    float psum[4] = {0.f, 0.f, 0.f, 0.f};
    f32x4 Ov[4];
    #pragma unroll
    for (int nt = 0; nt < 4; ++nt) Ov[nt] = (f32x4){0.f, 0.f, 0.f, 0.f};

    // prologue: tile 0 into registers
    bf16x8 kr1 = *(const bf16x8*)(khead + koff1);
    bf16x8 kr2 = *(const bf16x8*)(khead + koff2);
    bf16x8 vr1 = *(const bf16x8*)(vhead + voff1);
    bf16x8 vr2 = *(const bf16x8*)(vhead + voff2);

    for (int kt = 0; kt < 16; ++kt) {
        __syncthreads();                 // waves done reading tile kt-1
        *(bf16x8*)kw1 = kr1;
        *(bf16x8*)kw2 = kr2;
        *(bf16x8*)vw1 = vr1;
        *(bf16x8*)vw2 = vr2;
        if (kt < 15) {                   // issue tile kt+1 loads; land during compute
            const size_t kb = (size_t)(kt + 1) * 64;
            kr1 = *(const bf16x8*)(khead + kb * DH + koff1);
            kr2 = *(const bf16x8*)(khead + kb * DH + koff2);
            vr1 = *(const bf16x8*)(vhead + kb + voff1);
            vr2 = *(const bf16x8*)(vhead + kb + voff2);
        }
        __syncthreads();                 // publish tile kt

        f32x4 sa[4];
        __builtin_amdgcn_s_setprio(1);
        #pragma unroll
        for (int nt = 0; nt < 4; ++nt) {
            const bf16x8 kf0 = *(const bf16x8*)(Ks + (nt * 128 + quad * 16 + l15) * 8);
            const bf16x8 kf1 = *(const bf16x8*)(Ks + (nt * 128 + (quad + 4) * 16 + l15) * 8);
            sa[nt] = (f32x4){0.f, 0.f, 0.f, 0.f};
            sa[nt] = MFMA(qf0, kf0, sa[nt]);
            sa[nt] = MFMA(qf1, kf1, sa[nt]);
        }
        __builtin_amdgcn_s_setprio(0);

        #pragma unroll
        for (int nt = 0; nt < 4; ++nt) {
            #pragma unroll
            for (int r = 0; r < 4; ++r) {
                const float p = __builtin_exp2f(sa[nt][r]);   // SC2 pre-folded into Q
                psum[r] += p;
                Ps[w][(quad * 4 + r) * SP + nt * 16 + l15] = p;
            }
        }

        __builtin_amdgcn_s_setprio(1);
        #pragma unroll
        for (int kw = 0; kw < 2; ++kw) {
            const f32x4 pa = *(const f32x4*)&Ps[w][l15 * SP + kw * 32 + quad * 8];
            const f32x4 pb = *(const f32x4*)&Ps[w][l15 * SP + kw * 32 + quad * 8 + 4];
            bf16x8 pf;
            #pragma unroll
            for (int j = 0; j < 4; ++j) { pf[j] = (__bf16)pa[j]; pf[4 + j] = (__bf16)pb[j]; }
            #pragma unroll
            for (int nt = 0; nt < 4; ++nt) {
                const bf16x8 vf = *(const bf16x8*)(Vs + (nt * 128 + (kw * 4 + quad) * 16 + l15) * 8);
                Ov[nt] = MFMA(pf, vf, Ov[nt]);
            }
        }
        __builtin_amdgcn_s_setprio(0);
    }

    float lrow[4];
    #pragma unroll
    for (int r = 0; r < 4; ++r) {
        float lt = psum[r];
        lt += __shfl_xor(lt, 1);
        lt += __shfl_xor(lt, 2);
        lt += __shfl_xor(lt, 4);
        lt += __shfl_xor(lt, 8);
        lrow[r] = lt;
    }

    #pragma unroll
    for (int r = 0; r < 4; ++r) {
        const float inv = 1.0f / lrow[r];
        const int row = qt * 64 + w * 16 + quad * 4 + r;
        __bf16* op = ob + ((size_t)(b * H_ + h) * N_ + row) * DH + l15;
        #pragma unroll
        for (int nt = 0; nt < 4; ++nt)
            op[nt * 16] = (__bf16)(Ov[nt][r] * inv);
    }
}

// ---------------------------------------------------------------------------
extern "C" void kernel_launch(void* const* d_in, const int* in_sizes, int n_in,
                              void* d_out, int out_size, void* d_ws, size_t ws_size,
                              hipStream_t stream) {
    const float* x  = (const float*)d_in[0];
    const float* Wq = (const float*)d_in[1];
    const float* bq = (const float*)d_in[2];
    const float* Wk = (const float*)d_in[3];
    const float* bk = (const float*)d_in[4];
    const float* Wv = (const float*)d_in[5];
    const float* bv = (const float*)d_in[6];
    const float* Wc = (const float*)d_in[7];
    const float* bc = (const float*)d_in[8];
    float* out = (float*)d_out;

    // ws layout (48 MB):
    //   [ 0, 8MB): xb (bf16 4Mi) -- dead after QKV GEMM, reused as obf
    //   [ 8,14MB): wqkvb  [14,16MB): wcb
    //   [16,40MB): qkvb (q,k slabs [B,H,N,Dh]; q pre-scaled by SC2)
    //   [40,48MB): vT [B,H,Dh,N] (written directly by gemm_qkv256 V-part)
    char* base = (char*)d_ws;
    __bf16* xb    = (__bf16*)(base);
    __bf16* wqkvb = (__bf16*)(base + (size_t)8  * 1048576);
    __bf16* wcb   = (__bf16*)(base + (size_t)14 * 1048576);
    __bf16* qkvb  = (__bf16*)(base + (size_t)16 * 1048576);
    __bf16* vTb   = (__bf16*)(base + (size_t)40 * 1048576);
    __bf16* obf   = (__bf16*)(base);   // overwrites xb after attn

    __bf16* qhb = qkvb;
    __bf16* khb = qkvb + (size_t)M_ * D_;

    convert_k<<<dim3(4096), dim3(256), 0, stream>>>(
        x, Wq, Wk, Wv, Wc, xb, wqkvb, wcb);

    gemm_qkv256<<<dim3(192), dim3(512), 0, stream>>>(
        xb, wqkvb, bq, bk, bv, qkvb, vTb);

    attn_mfma<<<dim3(1024), dim3(256), 0, stream>>>(qhb, khb, vTb, obf);

    gemm_out<<<dim3(8, 64, 1), dim3(256), 0, stream>>>(obf, wcb, bc, out);
}

// Round 5
// 184.090 us; speedup vs baseline: 1.1124x; 1.0500x over previous
//
#include <hip/hip_runtime.h>
#include <cstddef>
#include <cstdint>

#define B_  4
#define N_  1024
#define D_  1024
#define H_  16
#define DH  64
#define M_  4096   // B_*N_

#define SC2 0.04508422f   // (1/32) * log2(e)  — folded into Q at gemm epilogue

typedef __attribute__((ext_vector_type(4)))  float   f32x4;
typedef __attribute__((ext_vector_type(16))) float   f32x16;
typedef __attribute__((ext_vector_type(8)))  __bf16  bf16x8;
typedef __attribute__((ext_vector_type(4)))  unsigned int u32x4;

#define MFMA(a, b, c)   __builtin_amdgcn_mfma_f32_16x16x32_bf16((a), (b), (c), 0, 0, 0)
#define MFMA32(a, b, c) __builtin_amdgcn_mfma_f32_32x32x16_bf16((a), (b), (c), 0, 0, 0)
#define GLDS(gp, lp) __builtin_amdgcn_global_load_lds( \
    (__attribute__((address_space(1))) void*)(gp),     \
    (__attribute__((address_space(3))) void*)(lp), 16, 0, 0)

static __device__ __forceinline__ unsigned cvtpk(float lo, float hi) {
    unsigned r;
    asm("v_cvt_pk_bf16_f32 %0, %1, %2" : "=v"(r) : "v"(lo), "v"(hi));
    return r;
}

// ---------------------------------------------------------------------------
// convert: fp32 -> bf16 for x (4Mi) and Wq/Wk/Wv/Wc (4x1Mi). [verified R3]
// ---------------------------------------------------------------------------
__global__ __launch_bounds__(256) void convert_k(
    const float* __restrict__ x,  const float* __restrict__ Wq,
    const float* __restrict__ Wk, const float* __restrict__ Wv,
    const float* __restrict__ Wc,
    __bf16* __restrict__ xb, __bf16* __restrict__ wqkvb,
    __bf16* __restrict__ wcb)
{
    const unsigned u = blockIdx.x * 256u + threadIdx.x;
    const unsigned e = u * 8u;
    const float* src;
    __bf16* dst;
    if (e < 4194304u) { src = x + e; dst = xb + e; }
    else {
        const unsigned t2 = e - 4194304u;
        const unsigned wsel = t2 >> 20;
        const unsigned wo = t2 & 1048575u;
        src = (wsel == 0 ? Wq : wsel == 1 ? Wk : wsel == 2 ? Wv : Wc) + wo;
        dst = (wsel < 3 ? wqkvb + (size_t)wsel * 1048576u : wcb) + wo;
    }
    const float4 f0 = *(const float4*)(src);
    const float4 f1 = *(const float4*)(src + 4);
    bf16x8 r;
    r[0] = (__bf16)f0.x; r[1] = (__bf16)f0.y; r[2] = (__bf16)f0.z; r[3] = (__bf16)f0.w;
    r[4] = (__bf16)f1.x; r[5] = (__bf16)f1.y; r[6] = (__bf16)f1.z; r[7] = (__bf16)f1.w;
    *(bf16x8*)dst = r;
}

// ---------------------------------------------------------------------------
// QKV GEMM — R12 8-phase 256^2 template [verified R12]. Q slab epilogue
// multiplies by SC2 (softmax scale folded into Q).
// ---------------------------------------------------------------------------
__global__ __launch_bounds__(512, 2) void gemm_qkv256(
    const __bf16* __restrict__ xb, const __bf16* __restrict__ Wb,
    const float* __restrict__ bq, const float* __restrict__ bk,
    const float* __restrict__ bv,
    __bf16* __restrict__ qk_out, __bf16* __restrict__ vT)
{
    __shared__ __bf16 ring[65536];   // [A: 4 x 8192][B: 4 x 8192] = 128KB

    const int tid  = threadIdx.x;
    const int w    = tid >> 6;        // 0..7
    const int lane = tid & 63;
    const int quad = lane >> 4;
    const int l15  = lane & 15;
    const int wr   = w >> 2;          // 0..1  (M half)
    const int wc   = w & 3;           // 0..3  (N quarter)

    const int bid = blockIdx.x;
    const bool VT = (bid >= 128);
    int m0, n0;
    const __bf16 *Ap, *Bp;
    if (!VT) { m0 = (bid >> 3) * 256; n0 = (bid & 7) * 256; Ap = xb; Bp = Wb; }
    else {
        const int v = bid - 128;
        m0 = (v & 3) * 256;           // over e (Wv rows)
        n0 = (v >> 2) * 256;          // over m (xb rows)
        Ap = Wb + (size_t)2 * D_ * D_; Bp = xb;
    }

    const size_t sgl = (size_t)(w * 16 + l15) * D_ + quad * 8;
    const __bf16* Asrc = Ap + (size_t)m0 * D_ + sgl;
    const __bf16* Bsrc = Bp + (size_t)n0 * D_ + sgl;
    __bf16* const ringA = ring;
    __bf16* const ringB = ring + 32768;
    const int sdst = w * 1024;

#define STG_A(tt, h) do {                                               \
    const __bf16* s_ = Asrc + (size_t)(h) * 128 * D_ + (tt) * 64;       \
    __bf16* d_ = ringA + ((((tt) & 1) * 2 + (h)) * 8192) + sdst;        \
    GLDS(s_, d_); GLDS(s_ + 32, d_ + 512); } while (0)
#define STG_B(tt, h) do {                                               \
    const __bf16* s_ = Bsrc + (size_t)(h) * 128 * D_ + (tt) * 64;       \
    __bf16* d_ = ringB + ((((tt) & 1) * 2 + (h)) * 8192) + sdst;        \
    GLDS(s_, d_); GLDS(s_ + 32, d_ + 512); } while (0)

    f32x4 acc[8][4];
    #pragma unroll
    for (int i = 0; i < 8; ++i)
        #pragma unroll
        for (int j = 0; j < 4; ++j)
            acc[i][j] = (f32x4){0.f, 0.f, 0.f, 0.f};

    // prologue: order matters for the vmcnt ledger (oldest = B(0))
    STG_B(0, 0); STG_B(0, 1);
    STG_A(0, 0); STG_A(0, 1);
    STG_B(1, 0); STG_B(1, 1);

    const int rdo = lane * 8;

#define READ_A(q)                                                       \
    afr[0][0] = *(const bf16x8*)(Asl + ((2*(q)  )*2 + 0)*512);          \
    afr[0][1] = *(const bf16x8*)(Asl + ((2*(q)  )*2 + 1)*512);          \
    afr[1][0] = *(const bf16x8*)(Asl + ((2*(q)+1)*2 + 0)*512);          \
    afr[1][1] = *(const bf16x8*)(Asl + ((2*(q)+1)*2 + 1)*512);

#define PHASE_MFMA(q)                                                   \
    __builtin_amdgcn_s_barrier();                                       \
    asm volatile("s_waitcnt lgkmcnt(0)" ::: "memory");                  \
    __builtin_amdgcn_s_setprio(1);                                      \
    _Pragma("unroll")                                                   \
    for (int i = 0; i < 2; ++i)                                         \
      _Pragma("unroll")                                                 \
      for (int nt = 0; nt < 4; ++nt) {                                  \
        acc[2*(q)+i][nt] = MFMA(afr[i][0], bfr[nt][0], acc[2*(q)+i][nt]); \
        acc[2*(q)+i][nt] = MFMA(afr[i][1], bfr[nt][1], acc[2*(q)+i][nt]); \
      }                                                                 \
    __builtin_amdgcn_s_setprio(0);

    for (int t = 0; t < 16; ++t) {
        if (t < 15) asm volatile("s_waitcnt vmcnt(4)" ::: "memory");
        else        asm volatile("s_waitcnt vmcnt(0)" ::: "memory");
        __builtin_amdgcn_s_barrier();

        const __bf16* Asl = ringA + ((t & 1) * 2 + wr) * 8192 + rdo;
        const __bf16* Bsl = ringB + ((t & 1) * 2 + (wc >> 1)) * 8192
                                  + (wc & 1) * 4096 + rdo;
        bf16x8 afr[2][2], bfr[4][2];

        // ---- phase 0 ----
        if (t < 15) STG_A(t + 1, 0);
        #pragma unroll
        for (int nt = 0; nt < 4; ++nt) {
            bfr[nt][0] = *(const bf16x8*)(Bsl + (nt * 2 + 0) * 512);
            bfr[nt][1] = *(const bf16x8*)(Bsl + (nt * 2 + 1) * 512);
        }
        READ_A(0)
        PHASE_MFMA(0)
        __builtin_amdgcn_s_barrier();

        // ---- phase 1 ----
        if (t < 15) STG_A(t + 1, 1);
        READ_A(1)
        PHASE_MFMA(1)
        __builtin_amdgcn_s_barrier();

        // ---- phase 2 ----
        if (t < 14) STG_B(t + 2, 0);
        READ_A(2)
        PHASE_MFMA(2)
        __builtin_amdgcn_s_barrier();

        // ---- phase 3 ----
        if (t < 14) STG_B(t + 2, 1);
        READ_A(3)
        PHASE_MFMA(3)
    }
#undef STG_A
#undef STG_B
#undef READ_A
#undef PHASE_MFMA

    if (!VT) {
        const int zq = n0 >> 10;                  // 0:Q 1:K
        const float* bias = zq ? bk : bq;
        const float qs = zq ? 1.0f : SC2;         // fold softmax scale into Q
        const int nb = (n0 & 1023) + wc * 64;
        float bvv[4];
        #pragma unroll
        for (int nt = 0; nt < 4; ++nt) bvv[nt] = bias[nb + nt * 16 + l15];
        __bf16* C = qk_out + (size_t)zq * M_ * D_;
        #pragma unroll
        for (int mt = 0; mt < 8; ++mt) {
            #pragma unroll
            for (int r = 0; r < 4; ++r) {
                const int row = m0 + wr * 128 + mt * 16 + quad * 4 + r;
                #pragma unroll
                for (int nt = 0; nt < 4; ++nt) {
                    const int col = nb + nt * 16 + l15;
                    const size_t idx = (((size_t)(row >> 10) * H_ + (col >> 6)) * N_
                                        + (row & 1023)) * DH + (col & 63);
                    C[idx] = (__bf16)((acc[mt][nt][r] + bvv[nt]) * qs);
                }
            }
        }
    } else {
        #pragma unroll
        for (int mt = 0; mt < 8; ++mt) {
            #pragma unroll
            for (int r = 0; r < 4; ++r) {
                const int row = m0 + wr * 128 + mt * 16 + quad * 4 + r;   // e
                const float brow = bv[row];
                #pragma unroll
                for (int nt = 0; nt < 4; ++nt) {
                    const int col = n0 + wc * 64 + nt * 16 + l15;         // m
                    const size_t idx = (((size_t)(col >> 10) * H_ + (row >> 6)) * DH
                                        + (row & 63)) * N_ + (col & 1023);
                    vT[idx] = (__bf16)(acc[mt][nt][r] + brow);
                }
            }
        }
    }
}

// ---------------------------------------------------------------------------
// Final projection GEMM — R10's gemm64 MODE0 path [verified; R11 ring null].
// ---------------------------------------------------------------------------
__global__ __launch_bounds__(256, 6) void gemm_out(
    const __bf16* __restrict__ A0, const __bf16* __restrict__ Wb,
    const float* __restrict__ b0, float* __restrict__ Cb)
{
    __shared__ __bf16 As[2048];   // 64x32, frag-ordered (4KB)
    __shared__ __bf16 Bs[4096];   // 128x32, frag-ordered (8KB)

    const int tid  = threadIdx.x;
    const int w    = tid >> 6;
    const int lane = tid & 63;
    const int quad = lane >> 4;
    const int l15  = lane & 15;
    const int wr   = w >> 1, wc = w & 1;

    const int m0 = blockIdx.y * 64;
    const int n0 = blockIdx.x * 128;

    const int Tt = tid >> 6, ko = (tid >> 4) & 3, l = tid & 15;
    const size_t aoff  = (size_t)(m0 + Tt * 16 + l) * D_ + ko * 8;
    const size_t boff1 = (size_t)(n0 + Tt * 16 + l) * D_ + ko * 8;
    const size_t boff2 = boff1 + (size_t)64 * D_;
    __bf16* adst  = As + w * 512;
    __bf16* bdst1 = Bs + w * 512;
    __bf16* bdst2 = Bs + 2048 + w * 512;

    f32x4 acc[2][4];
    #pragma unroll
    for (int i = 0; i < 2; ++i)
        #pragma unroll
        for (int j = 0; j < 4; ++j)
            acc[i][j] = (f32x4){0.f, 0.f, 0.f, 0.f};

    for (int k0 = 0; k0 < D_; k0 += 32) {
        GLDS(A0 + aoff  + k0, adst);
        GLDS(Wb + boff1 + k0, bdst1);
        GLDS(Wb + boff2 + k0, bdst2);
        __syncthreads();

        bf16x8 af[2], bf[4];
        #pragma unroll
        for (int mt = 0; mt < 2; ++mt)
            af[mt] = *(const bf16x8*)(As + (((wr * 2 + mt) * 4 + quad) * 16 + l15) * 8);
        #pragma unroll
        for (int nt = 0; nt < 4; ++nt)
            bf[nt] = *(const bf16x8*)(Bs + (((wc * 4 + nt) * 4 + quad) * 16 + l15) * 8);
        #pragma unroll
        for (int mt = 0; mt < 2; ++mt)
            #pragma unroll
            for (int nt = 0; nt < 4; ++nt)
                acc[mt][nt] = MFMA(af[mt], bf[nt], acc[mt][nt]);
        __syncthreads();
    }

    float bvv[4];
    #pragma unroll
    for (int nt = 0; nt < 4; ++nt)
        bvv[nt] = b0[n0 + wc * 64 + nt * 16 + l15];
    #pragma unroll
    for (int mt = 0; mt < 2; ++mt) {
        #pragma unroll
        for (int r = 0; r < 4; ++r) {
            const int row = m0 + (wr * 2 + mt) * 16 + quad * 4 + r;
            #pragma unroll
            for (int nt = 0; nt < 4; ++nt) {
                const int col = n0 + wc * 64 + nt * 16 + l15;
                Cb[(size_t)row * D_ + col] = acc[mt][nt][r] + bvv[nt];
            }
        }
    }
}

// ---------------------------------------------------------------------------
// MFMA flash attention v8 — R15: 32x32 swapped-QK^T, P fully in-register.
// Theory: R14 arithmetic shows the 16x16 loop is LDS-BW-bound (~31us of 45us
// on the LDS pipe: K/V frags re-read per 16-q wave + 20-op P round-trip).
// New structure: 32 q/wave via mfma_32x32x16. S^T = K.Q^T -> each lane holds
// P[*][q=lane&31] in regs (pair lane^32 splits keys). Softmax in-register;
// P->A-frag redistribution = 16 cvt_pk + 8 permlane32_swap per 64-key tile
// (T12). K read as A-frags, V (d-major vT) as B-frags, frag-ordered LDS
// (conflict-free 1KB wave reads). Per-q LDS traffic 1.5KB -> 0.5KB (3x).
// Layouts: A-frag row=lane&31,k=(lane>>5)*8+j; B-frag col=lane&31, same k;
// C col=lane&31, row=(reg&3)+8*(reg>>2)+4*(lane>>5) [m74/m101].
// swap(U=cvtpk(e0,e1), V=cvtpk(e4,e5)): U'={U.lo, V.lo}, V'={U.hi, V.hi}
// gives word0/word2 of both half-lanes' A-frags — ledger checked.
// Staging: T14 reg-staging, raw s_barrier + lgkmcnt(0)-only publish (R14's
// __syncthreads drained vmcnt(0), killing the prefetch — fixed here).
// 4 waves x 32 q = 128 q/block; grid 512 = 2 blocks/CU; LDS 16KB.
// ---------------------------------------------------------------------------
__global__ __launch_bounds__(256, 2) void attn_mfma(
    const __bf16* __restrict__ qh, const __bf16* __restrict__ kh,
    const __bf16* __restrict__ vT, __bf16* __restrict__ ob)
{
    __shared__ __align__(16) __bf16 Ks[4096];   // 8 frags x 512 elems (8KB)
    __shared__ __align__(16) __bf16 Vs[4096];   // 8 frags x 512 elems (8KB)

    const int tid  = threadIdx.x;
    const int w    = tid >> 6;        // 0..3
    const int lane = tid & 63;
    const int la31 = lane & 31;
    const int hi   = lane >> 5;       // 0/1

    const int bh = blockIdx.x >> 3;   // 0..63
    const int qt = blockIdx.x & 7;    // 128-q tile
    const int b  = bh >> 4;
    const int h  = bh & 15;

    const size_t headQ = (size_t)(b * H_ + h) * N_;

    // Q in registers: B-frag col=lane&31=q, k=d=(lane>>5)*8+j, dk*16 per frag
    const int qrow = qt * 128 + w * 32 + la31;
    const __bf16* qp = qh + (headQ + qrow) * DH + hi * 8;
    const bf16x8 qf0 = *(const bf16x8*)(qp);
    const bf16x8 qf1 = *(const bf16x8*)(qp + 16);
    const bf16x8 qf2 = *(const bf16x8*)(qp + 32);
    const bf16x8 qf3 = *(const bf16x8*)(qp + 48);

    const __bf16* khead = kh + headQ * DH;                    // [N][64]
    const __bf16* vhead = vT + (size_t)(b * H_ + h) * DH * N_; // [64][N]

    // staging: 4 chunks/thread (16B). Chunk c <-> LDS elems c*8 (frag-ordered).
    // K frag f=s*4+dk: lane needs K[s*32+(l&31)][dk*16+(l>>5)*8+j]
    // V frag g=kb*2+d0: lane needs vT[d0*32+(l&31)][kb*16+(l>>5)*8+j]
    const size_t koff0 = (size_t)la31 * DH + w * 16 + hi * 8;           // f=w (s=0,dk=w)
    const size_t koff1 = koff0 + (size_t)32 * DH;                       // f=w+4 (s=1)
    const size_t voff0 = (size_t)((w & 1) * 32 + la31) * N_ + (w >> 1) * 16 + hi * 8;
    const size_t voff1 = voff0 + 32;                                    // g=w+4: kb+=2
    __bf16* const kd0 = Ks + tid * 8;
    __bf16* const kd1 = Ks + tid * 8 + 2048;
    __bf16* const vd0 = Vs + tid * 8;
    __bf16* const vd1 = Vs + tid * 8 + 2048;

    f32x16 Ov0, Ov1;
    #pragma unroll
    for (int r = 0; r < 16; ++r) { Ov0[r] = 0.f; Ov1[r] = 0.f; }
    float psum = 0.f;

    // prologue: tile 0 -> regs
    bf16x8 kr0 = *(const bf16x8*)(khead + koff0);
    bf16x8 kr1 = *(const bf16x8*)(khead + koff1);
    bf16x8 vr0 = *(const bf16x8*)(vhead + voff0);
    bf16x8 vr1 = *(const bf16x8*)(vhead + voff1);

#define PACK(earr, base, dst) do {                                        \
    unsigned U_ = cvtpk(earr[(base) + 0], earr[(base) + 1]);              \
    unsigned W_ = cvtpk(earr[(base) + 2], earr[(base) + 3]);              \
    unsigned V_ = cvtpk(earr[(base) + 4], earr[(base) + 5]);              \
    unsigned Z_ = cvtpk(earr[(base) + 6], earr[(base) + 7]);              \
    asm volatile("v_permlane32_swap_b32 %0, %1" : "+v"(U_), "+v"(V_));    \
    asm volatile("v_permlane32_swap_b32 %0, %1" : "+v"(W_), "+v"(Z_));    \
    u32x4 pw_ = {U_, W_, V_, Z_};                                         \
    dst = __builtin_bit_cast(bf16x8, pw_);                                \
} while (0)

    for (int kt = 0; kt < 16; ++kt) {
        asm volatile("s_waitcnt lgkmcnt(0)" ::: "memory");
        __builtin_amdgcn_s_barrier();            // all waves done reading prev tile
        __builtin_amdgcn_sched_barrier(0);

        *(bf16x8*)kd0 = kr0;                     // waits vmcnt on kr/vr (compiler)
        *(bf16x8*)kd1 = kr1;
        *(bf16x8*)vd0 = vr0;
        *(bf16x8*)vd1 = vr1;
        if (kt < 15) {                           // issue next-tile loads; stay in flight
            const __bf16* kp = khead + (size_t)(kt + 1) * 64 * DH;
            const __bf16* vp = vhead + (size_t)(kt + 1) * 64;
            kr0 = *(const bf16x8*)(kp + koff0);
            kr1 = *(const bf16x8*)(kp + koff1);
            vr0 = *(const bf16x8*)(vp + voff0);
            vr1 = *(const bf16x8*)(vp + voff1);
        }
        asm volatile("s_waitcnt lgkmcnt(0)" ::: "memory");   // publish ds_writes ONLY
        __builtin_amdgcn_s_barrier();
        __builtin_amdgcn_sched_barrier(0);

        // ---- QK^T (swapped): sa = K . Q^T, contraction over d=64 ----
        f32x16 sa0, sa1;
        __builtin_amdgcn_s_setprio(1);
        {
            f32x16 z;
            #pragma unroll
            for (int r = 0; r < 16; ++r) z[r] = 0.f;
            bf16x8 kf;
            kf = *(const bf16x8*)(Ks + 0 * 512 + lane * 8); sa0 = MFMA32(kf, qf0, z);
            kf = *(const bf16x8*)(Ks + 1 * 512 + lane * 8); sa0 = MFMA32(kf, qf1, sa0);
            kf = *(const bf16x8*)(Ks + 2 * 512 + lane * 8); sa0 = MFMA32(kf, qf2, sa0);
            kf = *(const bf16x8*)(Ks + 3 * 512 + lane * 8); sa0 = MFMA32(kf, qf3, sa0);
            kf = *(const bf16x8*)(Ks + 4 * 512 + lane * 8); sa1 = MFMA32(kf, qf0, z);
            kf = *(const bf16x8*)(Ks + 5 * 512 + lane * 8); sa1 = MFMA32(kf, qf1, sa1);
            kf = *(const bf16x8*)(Ks + 6 * 512 + lane * 8); sa1 = MFMA32(kf, qf2, sa1);
            kf = *(const bf16x8*)(Ks + 7 * 512 + lane * 8); sa1 = MFMA32(kf, qf3, sa1);
        }
        __builtin_amdgcn_s_setprio(0);

        // ---- softmax (no max-sub, SC2 pre-folded): exp2 + in-reg psum ----
        float e0[16], e1[16];
        #pragma unroll
        for (int r = 0; r < 16; ++r) { e0[r] = __builtin_exp2f(sa0[r]); psum += e0[r]; }
        #pragma unroll
        for (int r = 0; r < 16; ++r) { e1[r] = __builtin_exp2f(sa1[r]); psum += e1[r]; }

        // ---- P -> A-frags: cvt_pk + permlane32_swap (T12) ----
        bf16x8 pf0, pf1, pf2, pf3;     // kb = 0..3 (16-key contraction blocks)
        PACK(e0, 0, pf0);
        PACK(e0, 8, pf1);
        PACK(e1, 0, pf2);
        PACK(e1, 8, pf3);

        // ---- PV: O += P . V ----
        __builtin_amdgcn_s_setprio(1);
        {
            bf16x8 vf;
            vf = *(const bf16x8*)(Vs + 0 * 512 + lane * 8); Ov0 = MFMA32(pf0, vf, Ov0);
            vf = *(const bf16x8*)(Vs + 2 * 512 + lane * 8); Ov0 = MFMA32(pf1, vf, Ov0);
            vf = *(const bf16x8*)(Vs + 4 * 512 + lane * 8); Ov0 = MFMA32(pf2, vf, Ov0);
            vf = *(const bf16x8*)(Vs + 6 * 512 + lane * 8); Ov0 = MFMA32(pf3, vf, Ov0);
            vf = *(const bf16x8*)(Vs + 1 * 512 + lane * 8); Ov1 = MFMA32(pf0, vf, Ov1);
            vf = *(const bf16x8*)(Vs + 3 * 512 + lane * 8); Ov1 = MFMA32(pf1, vf, Ov1);
            vf = *(const bf16x8*)(Vs + 5 * 512 + lane * 8); Ov1 = MFMA32(pf2, vf, Ov1);
            vf = *(const bf16x8*)(Vs + 7 * 512 + lane * 8); Ov1 = MFMA32(pf3, vf, Ov1);
        }
        __builtin_amdgcn_s_setprio(0);
    }
#undef PACK

    // lane pair (l, l^32) holds the two key-halves of query q=lane&31
    psum += __shfl_xor(psum, 32);
    const float inv = 1.0f / psum;

    __bf16* const obase = ob + (headQ + qt * 128 + w * 32) * DH;
    #pragma unroll
    for (int r = 0; r < 16; ++r) {
        const int q_r = (r & 3) + 8 * (r >> 2) + 4 * hi;   // C-row [m74/m101]
        const float ivr = __shfl(inv, q_r);                // inv lives in lane q_r
        __bf16* op = obase + (size_t)q_r * DH + la31;
        op[0]  = (__bf16)(Ov0[r] * ivr);
        op[32] = (__bf16)(Ov1[r] * ivr);
    }
}

// ---------------------------------------------------------------------------
extern "C" void kernel_launch(void* const* d_in, const int* in_sizes, int n_in,
                              void* d_out, int out_size, void* d_ws, size_t ws_size,
                              hipStream_t stream) {
    const float* x  = (const float*)d_in[0];
    const float* Wq = (const float*)d_in[1];
    const float* bq = (const float*)d_in[2];
    const float* Wk = (const float*)d_in[3];
    const float* bk = (const float*)d_in[4];
    const float* Wv = (const float*)d_in[5];
    const float* bv = (const float*)d_in[6];
    const float* Wc = (const float*)d_in[7];
    const float* bc = (const float*)d_in[8];
    float* out = (float*)d_out;

    // ws layout (48 MB):
    //   [ 0, 8MB): xb (bf16 4Mi) -- dead after QKV GEMM, reused as obf
    //   [ 8,14MB): wqkvb  [14,16MB): wcb
    //   [16,40MB): qkvb (q,k slabs [B,H,N,Dh]; q pre-scaled by SC2)
    //   [40,48MB): vT [B,H,Dh,N] (written directly by gemm_qkv256 V-part)
    char* base = (char*)d_ws;
    __bf16* xb    = (__bf16*)(base);
    __bf16* wqkvb = (__bf16*)(base + (size_t)8  * 1048576);
    __bf16* wcb   = (__bf16*)(base + (size_t)14 * 1048576);
    __bf16* qkvb  = (__bf16*)(base + (size_t)16 * 1048576);
    __bf16* vTb   = (__bf16*)(base + (size_t)40 * 1048576);
    __bf16* obf   = (__bf16*)(base);   // overwrites xb after attn

    __bf16* qhb = qkvb;
    __bf16* khb = qkvb + (size_t)M_ * D_;

    convert_k<<<dim3(4096), dim3(256), 0, stream>>>(
        x, Wq, Wk, Wv, Wc, xb, wqkvb, wcb);

    gemm_qkv256<<<dim3(192), dim3(512), 0, stream>>>(
        xb, wqkvb, bq, bk, bv, qkvb, vTb);

    attn_mfma<<<dim3(512), dim3(256), 0, stream>>>(qhb, khb, vTb, obf);

    gemm_out<<<dim3(8, 64, 1), dim3(256), 0, stream>>>(obf, wcb, bc, out);
}